// Round 1
// baseline (3046.574 us; speedup 1.0000x reference)
//
#include <hip/hip_runtime.h>
#include <math.h>

#define V_WORDS 20000
#define MM 32
#define EE 128
#define HH 4
#define DHH 32
#define NN 8192
#define LL 64
#define CC 128

typedef short bf16x8 __attribute__((ext_vector_type(8)));
typedef float f32x4 __attribute__((ext_vector_type(4)));
typedef unsigned short u16;
typedef unsigned int u32;

__device__ __forceinline__ u16 f2bf(float x) {
    u32 u = __float_as_uint(x);
    u32 r = (u + 0x7FFFu + ((u >> 16) & 1u)) >> 16;
    return (u16)r;
}
__device__ __forceinline__ float bflo(u32 u) { return __uint_as_float(u << 16); }
__device__ __forceinline__ float bfhi(u32 u) { return __uint_as_float(u & 0xFFFF0000u); }

// ---------------------------------------------------------------------------
// Kernel 0: pack conv weights into bf16 MFMA B-fragment order (unchanged).
// ---------------------------------------------------------------------------
__global__ __launch_bounds__(256)
void pack_weights(const float* __restrict__ w3,
                  const float* __restrict__ w4,
                  const float* __restrict__ w5,
                  u16* __restrict__ Bpack)
{
    const int s = blockIdx.x;
    const int t = threadIdx.x;
    const int lane = t & 63;

    const float* src;
    int K, sl;
    if (s < 12)      { src = w3; K = 3; sl = s; }
    else if (s < 28) { src = w4; K = 4; sl = s - 12; }
    else             { src = w5; K = 5; sl = s - 28; }
    const int j  = sl >> 2;
    const int e0 = (sl & 3) * 32;

    for (int nt = (t >> 6); nt < 8; nt += 4) {
        const int c = nt * 16 + (lane & 15);
        const int kb = (lane >> 4) * 8;
        u16 vals[8];
        #pragma unroll
        for (int i = 0; i < 8; ++i) {
            const int e = e0 + kb + i;
            vals[i] = f2bf(src[(c * EE + e) * K + j]);
        }
        u16* dst = Bpack + (((size_t)s * 8 + nt) * 64 + lane) * 8;
        *(bf16x8*)dst = *(const bf16x8*)vals;
    }
}

// ---------------------------------------------------------------------------
// Kernel A (fallback, ws too small): Kn/Vn projections (R15 path).
// ---------------------------------------------------------------------------
__global__ __launch_bounds__(256)
void kv_proj_kernel(const float* __restrict__ table,
                    const float* __restrict__ in_w,
                    const float* __restrict__ in_b,
                    u16* __restrict__ Kn16, u16* __restrict__ Vn16)
{
    const int n0 = blockIdx.x * 8;
    const int t = threadIdx.x;
    __shared__ float tbl[8][EE];
    {
        const int r = t >> 5, q4 = (t & 31) * 4;
        *(float4*)&tbl[r][q4] = *(const float4*)&table[(size_t)(n0 + r) * EE + q4];
    }
    __syncthreads();

    const int sel = t >> 7;
    const int i = t & 127;
    const float* w = in_w + (size_t)(sel + 1) * EE * EE + (size_t)i * EE;
    const float bias = in_b[(sel + 1) * EE + i];

    float acc[8];
    #pragma unroll
    for (int r = 0; r < 8; ++r) acc[r] = bias;
    for (int k = 0; k < EE; k += 4) {
        const float4 wv = *(const float4*)&w[k];
        #pragma unroll
        for (int r = 0; r < 8; ++r) {
            acc[r] += tbl[r][k]     * wv.x + tbl[r][k + 1] * wv.y
                    + tbl[r][k + 2] * wv.z + tbl[r][k + 3] * wv.w;
        }
    }
    u16* dst = sel ? Vn16 : Kn16;
    #pragma unroll
    for (int r = 0; r < 8; ++r) dst[(size_t)(n0 + r) * EE + i] = f2bf(acc[r]);
}

// ---------------------------------------------------------------------------
// Kernel A'' (R19): Q/K/W projections over the 8192 distinct news rows.
// ---------------------------------------------------------------------------
__global__ __launch_bounds__(384)
void kvqw_proj_kernel(const float* __restrict__ table,
                      const float* __restrict__ in_w,
                      const float* __restrict__ in_b,
                      const float* __restrict__ out_w,
                      const float* __restrict__ out_b,
                      u16* __restrict__ Qn16,
                      u16* __restrict__ Kn16,
                      u16* __restrict__ Wn16)
{
    const int n0 = blockIdx.x * 8;
    const int t = threadIdx.x;
    __shared__ float tbl[8][EE];
    __shared__ float vsh[8][EE];
    if (t < 256) {
        const int r = t >> 5, q4 = (t & 31) * 4;
        *(float4*)&tbl[r][q4] = *(const float4*)&table[(size_t)(n0 + r) * EE + q4];
    }
    __syncthreads();

    const int sel = t >> 7;                 // 0 = Q, 1 = K, 2 = V
    const int i = t & 127;
    const float* w = in_w + (size_t)sel * EE * EE + (size_t)i * EE;
    const float bias = in_b[sel * EE + i];

    float acc[8];
    #pragma unroll
    for (int r = 0; r < 8; ++r) acc[r] = bias;
    for (int k = 0; k < EE; k += 4) {
        const float4 wv = *(const float4*)&w[k];
        #pragma unroll
        for (int r = 0; r < 8; ++r) {
            acc[r] += tbl[r][k]     * wv.x + tbl[r][k + 1] * wv.y
                    + tbl[r][k + 2] * wv.z + tbl[r][k + 3] * wv.w;
        }
    }
    if (sel == 0) {
        #pragma unroll
        for (int r = 0; r < 8; ++r) Qn16[(size_t)(n0 + r) * EE + i] = f2bf(acc[r]);
    } else if (sel == 1) {
        #pragma unroll
        for (int r = 0; r < 8; ++r) Kn16[(size_t)(n0 + r) * EE + i] = f2bf(acc[r]);
    } else {
        #pragma unroll
        for (int r = 0; r < 8; ++r) vsh[r][i] = acc[r];   // keep V fp32 for phase 2
    }
    __syncthreads();

    // Phase 2: Wn[r][i] = vsh[r] . out_w[i] + out_b[i]
    {
        const int g = t >> 7;
        const int r0 = g, r1 = g + 3, r2 = g + 6;       // r2 == 8 invalid for g==2
        const int r2c = (r2 < 8) ? r2 : 7;
        const float* wr = out_w + (size_t)i * EE;
        const float ob = out_b[i];
        float a0 = ob, a1 = ob, a2 = ob;
        #pragma unroll 4
        for (int k = 0; k < EE; k += 4) {
            const float4 wv = *(const float4*)&wr[k];
            a0 += vsh[r0][k]   * wv.x + vsh[r0][k+1] * wv.y
                + vsh[r0][k+2] * wv.z + vsh[r0][k+3] * wv.w;
            a1 += vsh[r1][k]   * wv.x + vsh[r1][k+1] * wv.y
                + vsh[r1][k+2] * wv.z + vsh[r1][k+3] * wv.w;
            a2 += vsh[r2c][k]   * wv.x + vsh[r2c][k+1] * wv.y
                + vsh[r2c][k+2] * wv.z + vsh[r2c][k+3] * wv.w;
        }
        Wn16[(size_t)(n0 + r0) * EE + i] = f2bf(a0);
        Wn16[(size_t)(n0 + r1) * EE + i] = f2bf(a1);
        if (r2 < 8) Wn16[(size_t)(n0 + r2) * EE + i] = f2bf(a2);
    }
}

// ---------------------------------------------------------------------------
// Kernel B (fallback): per-word attention, R15 path (unchanged).
// ---------------------------------------------------------------------------
#define WPB 8
__global__ __launch_bounds__(256, 3)
void word_attn_kernel(const int* __restrict__ word2news,
                      const int* __restrict__ word2news_len,
                      const float* __restrict__ table,
                      const float* __restrict__ in_w,
                      const float* __restrict__ in_b,
                      const float* __restrict__ out_w,
                      const float* __restrict__ out_b,
                      const u16* __restrict__ Kn16,
                      const u16* __restrict__ Vn16,
                      u16* __restrict__ we16)
{
    const int v0 = blockIdx.x * WPB;
    const int t = threadIdx.x;

    __shared__ int   rows[WPB][MM];
    __shared__ int   lenS[WPB];
    __shared__ float q[WPB][EE];
    __shared__ float qh[WPB][EE];
    __shared__ float attn[WPB][HH][MM];
    __shared__ float osh[WPB][EE];

    {
        const int w = t >> 5, m = t & 31;
        rows[w][m] = word2news[(size_t)(v0 + w) * MM + m];
        if (t < WPB) lenS[t] = word2news_len[v0 + t];
    }
    __syncthreads();

    {
        const int w = t >> 5, d0 = (t & 31) * 4;
        const int L = lenS[w];
        float4 a = {0.f, 0.f, 0.f, 0.f};
        #pragma unroll 4
        for (int m = 0; m < MM; ++m) {
            const float4 x = *(const float4*)&table[(size_t)rows[w][m] * EE + d0];
            if (m < L) { a.x += x.x; a.y += x.y; a.z += x.z; a.w += x.w; }
        }
        const float inv = (L > 0) ? 1.0f / (float)L : 0.0f;
        a.x *= inv; a.y *= inv; a.z *= inv; a.w *= inv;
        *(float4*)&q[w][d0] = a;
    }
    __syncthreads();

    {
        const int g = t >> 7, i = t & 127;
        const float* wr = in_w + (size_t)i * EE;
        float acc[4] = {0.f, 0.f, 0.f, 0.f};
        #pragma unroll 4
        for (int k = 0; k < EE; k += 4) {
            const float4 wv = *(const float4*)&wr[k];
            #pragma unroll
            for (int w4 = 0; w4 < 4; ++w4) {
                const float* qw = q[g * 4 + w4];
                acc[w4] += qw[k] * wv.x + qw[k + 1] * wv.y
                         + qw[k + 2] * wv.z + qw[k + 3] * wv.w;
            }
        }
        const float b = in_b[i];
        #pragma unroll
        for (int w4 = 0; w4 < 4; ++w4) qh[g * 4 + w4][i] = acc[w4] + b;
    }
    __syncthreads();

    {
        const int w = t >> 5, m = t & 31;
        const int L = lenS[w];
        float s[HH] = {-1e9f, -1e9f, -1e9f, -1e9f};
        if (m < L) {
            const uint4* kr = (const uint4*)(Kn16 + (size_t)rows[w][m] * EE);
            #pragma unroll 1
            for (int h = 0; h < HH; ++h) {
                float a = 0.f;
                #pragma unroll
                for (int k8 = 0; k8 < 4; ++k8) {
                    const uint4 u = kr[h * 4 + k8];
                    const float4 q0 = *(const float4*)&qh[w][h * 32 + k8 * 8];
                    const float4 q1 = *(const float4*)&qh[w][h * 32 + k8 * 8 + 4];
                    a += q0.x * bflo(u.x) + q0.y * bfhi(u.x)
                       + q0.z * bflo(u.y) + q0.w * bfhi(u.y)
                       + q1.x * bflo(u.z) + q1.y * bfhi(u.z)
                       + q1.z * bflo(u.w) + q1.w * bfhi(u.w);
                }
                s[h] = a * 0.17677669529663687f;
            }
        }
        #pragma unroll
        for (int h = 0; h < HH; ++h) {
            float mx = s[h];
            #pragma unroll
            for (int off = 16; off > 0; off >>= 1)
                mx = fmaxf(mx, __shfl_xor(mx, off, 32));
            const float ex = expf(s[h] - mx);
            float sum = ex;
            #pragma unroll
            for (int off = 16; off > 0; off >>= 1)
                sum += __shfl_xor(sum, off, 32);
            attn[w][h][m] = ex / sum;
        }
    }
    __syncthreads();

    {
        const int w = t >> 5, d0 = (t & 31) * 4;
        const int h = d0 >> 5;
        float4 a = {0.f, 0.f, 0.f, 0.f};
        #pragma unroll 4
        for (int m = 0; m < MM; ++m) {
            const float aw = attn[w][h][m];
            const u32* vr = (const u32*)(Vn16 + (size_t)rows[w][m] * EE + d0);
            const u32 u0 = vr[0], u1 = vr[1];
            a.x += aw * bflo(u0); a.y += aw * bfhi(u0);
            a.z += aw * bflo(u1); a.w += aw * bfhi(u1);
        }
        *(float4*)&osh[w][d0] = a;
    }
    __syncthreads();

    {
        const int g = t >> 7, i = t & 127;
        const float* wr = out_w + (size_t)i * EE;
        float acc[4] = {0.f, 0.f, 0.f, 0.f};
        #pragma unroll 4
        for (int k = 0; k < EE; k += 4) {
            const float4 wv = *(const float4*)&wr[k];
            #pragma unroll
            for (int w4 = 0; w4 < 4; ++w4) {
                const float* ow = osh[g * 4 + w4];
                acc[w4] += ow[k] * wv.x + ow[k + 1] * wv.y
                         + ow[k + 2] * wv.z + ow[k + 3] * wv.w;
            }
        }
        const float b = out_b[i];
        #pragma unroll
        for (int w4 = 0; w4 < 4; ++w4) {
            const int w = g * 4 + w4;
            we16[(size_t)(v0 + w) * EE + i] =
                (lenS[w] > 0) ? f2bf(acc[w4] + b) : (u16)0;
        }
    }
}

// ---------------------------------------------------------------------------
// Kernel B'' (R20): per-word attention, fully fused. R20 changes: deeper
// in-flight gather loads everywhere (this kernel is L2/L3 gather-latency
// bound): Q-mean unroll 4->8 with explicit 8B loads; score phase prefetches
// 8x uint4 (a head-PAIR's K data) before any FMA instead of 4 per head;
// W phase unroll 4->8 with explicit 8B loads.
// ---------------------------------------------------------------------------
__global__ __launch_bounds__(256, 3)
void word_attn_wn(const int* __restrict__ word2news,
                  const int* __restrict__ word2news_len,
                  const u16* __restrict__ Qn16,
                  const u16* __restrict__ Kn16,
                  const u16* __restrict__ Wn16,
                  u16* __restrict__ we16)
{
    const int v0 = blockIdx.x * WPB;
    const int t = threadIdx.x;

    __shared__ int   rows[WPB][MM];
    __shared__ int   lenS[WPB];
    __shared__ float qh[WPB][EE];
    __shared__ float attn[WPB][HH][MM];

    {
        const int w = t >> 5, m = t & 31;
        rows[w][m] = word2news[(size_t)(v0 + w) * MM + m];
        if (t < WPB) lenS[t] = word2news_len[v0 + t];
    }
    __syncthreads();

    // qh = mean of gathered Qn rows (bias included; exact — weights sum to 1)
    {
        const int w = t >> 5, d0 = (t & 31) * 4;
        const int L = lenS[w];
        float4 a = {0.f, 0.f, 0.f, 0.f};
        #pragma unroll 8
        for (int m = 0; m < MM; ++m) {
            const uint2 u = *(const uint2*)(Qn16 + (size_t)rows[w][m] * EE + d0);
            if (m < L) {
                a.x += bflo(u.x); a.y += bfhi(u.x);
                a.z += bflo(u.y); a.w += bfhi(u.y);
            }
        }
        const float inv = (L > 0) ? 1.0f / (float)L : 0.0f;
        a.x *= inv; a.y *= inv; a.z *= inv; a.w *= inv;
        *(float4*)&qh[w][d0] = a;
    }
    __syncthreads();

    // scores (gather Kn rows) + softmax over m; head-PAIR at a time with the
    // pair's 8 uint4 (128B) prefetched before any FMA -> 8 loads in flight.
    {
        const int w = t >> 5, m = t & 31;
        const int L = lenS[w];
        float s[HH] = {-1e9f, -1e9f, -1e9f, -1e9f};
        if (m < L) {
            const uint4* kr = (const uint4*)(Kn16 + (size_t)rows[w][m] * EE);
            #pragma unroll
            for (int hp = 0; hp < 2; ++hp) {
                uint4 kq[8];
                #pragma unroll
                for (int q8 = 0; q8 < 8; ++q8) kq[q8] = kr[hp * 8 + q8];
                #pragma unroll
                for (int hl = 0; hl < 2; ++hl) {
                    const int h = hp * 2 + hl;
                    float a = 0.f;
                    #pragma unroll
                    for (int k8 = 0; k8 < 4; ++k8) {
                        const uint4 u = kq[hl * 4 + k8];
                        const float4 q0 = *(const float4*)&qh[w][h * 32 + k8 * 8];
                        const float4 q1 = *(const float4*)&qh[w][h * 32 + k8 * 8 + 4];
                        a += q0.x * bflo(u.x) + q0.y * bfhi(u.x)
                           + q0.z * bflo(u.y) + q0.w * bfhi(u.y)
                           + q1.x * bflo(u.z) + q1.y * bfhi(u.z)
                           + q1.z * bflo(u.w) + q1.w * bfhi(u.w);
                    }
                    s[h] = a * 0.17677669529663687f;
                }
            }
        }
        #pragma unroll
        for (int h = 0; h < HH; ++h) {
            float mx = s[h];
            #pragma unroll
            for (int off = 16; off > 0; off >>= 1)
                mx = fmaxf(mx, __shfl_xor(mx, off, 32));
            const float ex = expf(s[h] - mx);      // masked lanes underflow to 0
            float sum = ex;
            #pragma unroll
            for (int off = 16; off > 0; off >>= 1)
                sum += __shfl_xor(sum, off, 32);
            attn[w][h][m] = ex / sum;
        }
    }
    __syncthreads();

    // we = sum_m attn_m * Wn[rows[m]]  (out-proj + bias pre-folded into Wn)
    {
        const int w = t >> 5, d0 = (t & 31) * 4;
        const int h = d0 >> 5;
        const int L = lenS[w];
        float4 a = {0.f, 0.f, 0.f, 0.f};
        #pragma unroll 8
        for (int m = 0; m < MM; ++m) {
            const float aw = attn[w][h][m];
            const uint2 u = *(const uint2*)(Wn16 + (size_t)rows[w][m] * EE + d0);
            a.x += aw * bflo(u.x); a.y += aw * bfhi(u.x);
            a.z += aw * bflo(u.y); a.w += aw * bfhi(u.y);
        }
        u32 lo = 0u, hi = 0u;
        if (L > 0) {
            lo = (u32)f2bf(a.x) | ((u32)f2bf(a.y) << 16);
            hi = (u32)f2bf(a.z) | ((u32)f2bf(a.w) << 16);
        }
        u32* dst = (u32*)(we16 + (size_t)(v0 + w) * EE + d0);
        dst[0] = lo; dst[1] = hi;
    }
}

// ---------------------------------------------------------------------------
// Kernel 2: implicit-GEMM conv. R20: fully unroll the K-step loop (was
// unroll 2) — with NSL compile-time, every ds_read offset (j*272 + e0*64 +
// mt*4096 + g*16 <= 16b imm) and every Bpack offset folds to immediates,
// deleting most per-iteration VALU address math (VALUBusy was 36.5%).
// LDS bank conflicts (1.26e7 = exactly 4/instr) are modeled as the
// structural 4-way aliasing of the 16-row x 4-kslice b128 fragment read —
// predicted invariant under this change (this round tests that).
// ---------------------------------------------------------------------------
#define DSTRIDE 136              // u16 per doc row (16B-aligned, 68 words)
#define DOCSZ   (68 * DSTRIDE)   // u16 per doc (64 data rows + 4 zero rows)

template<int NSL, int SBASE, int NP>
__device__ __forceinline__ void conv_g2(const u16* __restrict__ lds,
                                        const u16* __restrict__ Bpack,
                                        const float* __restrict__ bk,
                                        int p, int nth, int l,
                                        float (&mxout)[4])
{
    f32x4 acc[4][4];
    #pragma unroll
    for (int mt = 0; mt < 4; ++mt)
        #pragma unroll
        for (int k = 0; k < 4; ++k)
            acc[mt][k] = (f32x4){0.f, 0.f, 0.f, 0.f};

    const int lm = l & 15;
    const int g  = l >> 4;
    const u16* bbase = Bpack + ((size_t)SBASE * 8 + nth * 4) * 512 + l * 8;
    const u16* abase = lds + (size_t)p * DOCSZ;

    #pragma unroll
    for (int s = 0; s < NSL; ++s) {
        const int j  = s >> 2;
        const int e0 = (s & 3) * 32;

        bf16x8 b[4];
        #pragma unroll
        for (int k = 0; k < 4; ++k)
            b[k] = *(const bf16x8*)(bbase + s * 4096 + k * 512);

        const u16* arow = abase + (lm + j) * DSTRIDE + e0 + g * 8;
        bf16x8 a[4];
        #pragma unroll
        for (int mt = 0; mt < 4; ++mt)
            a[mt] = *(const bf16x8*)(arow + mt * (16 * DSTRIDE));

        #pragma unroll
        for (int mt = 0; mt < 4; ++mt)
            #pragma unroll
            for (int k = 0; k < 4; ++k)
                acc[mt][k] = __builtin_amdgcn_mfma_f32_16x16x32_bf16(a[mt], b[k], acc[mt][k], 0, 0, 0);
    }

    #pragma unroll
    for (int k = 0; k < 4; ++k) {
        const int c = nth * 64 + k * 16 + lm;
        const float bias = bk[c];
        float mx = 0.0f;                     // relu output >= 0
        #pragma unroll
        for (int mt = 0; mt < 4; ++mt) {
            #pragma unroll
            for (int r = 0; r < 4; ++r) {
                const int pos = 16 * mt + g * 4 + r;
                const float y = fmaxf(acc[mt][k][r] + bias, 0.0f);
                if (pos < NP) mx = fmaxf(mx, y);
            }
        }
        mx = fmaxf(mx, __shfl_xor(mx, 16));
        mx = fmaxf(mx, __shfl_xor(mx, 32));
        mxout[k] = mx;
    }
}

__global__ __launch_bounds__(512, 4)
void news_kernel(const int* __restrict__ news_words,
                 const u16* __restrict__ we16,
                 const u16* __restrict__ Bpack,
                 const float* __restrict__ b3,
                 const float* __restrict__ b4,
                 const float* __restrict__ b5,
                 const float* __restrict__ fcw, const float* __restrict__ fcb,
                 float* __restrict__ out)
{
    const int n0 = blockIdx.x * 4;
    const int t = threadIdx.x;
    const int w = t >> 6, l = t & 63;
    const int p = w >> 1, nth = w & 1;

    __shared__ u16 lds[4 * DOCSZ];           // 73,984 B; feats alias after convs
    __shared__ int rows[4 * LL];

    if (t < 4 * LL) rows[t] = news_words[(size_t)n0 * LL + t];
    __syncthreads();

    {
        const uint4* weU = (const uint4*)we16;     // 16 uint4 per doc row
        uint4* ldsU = (uint4*)lds;                 // doc stride 1156 uint4
        for (int idx = t; idx < 4096; idx += 512) {
            const int d = idx >> 10, rem = idx & 1023;
            const int row = rem >> 4, c4 = rem & 15;
            ldsU[d * 1156 + row * 17 + c4] = weU[(size_t)rows[d * 64 + row] * 16 + c4];
        }
        if (t < 256) {                             // 4 docs x 4 pad rows x 16
            const int d = t >> 6, rem = t & 63;
            const int row = 64 + (rem >> 4), c4 = rem & 15;
            ldsU[d * 1156 + row * 17 + c4] = (uint4){0u, 0u, 0u, 0u};
        }
    }
    __syncthreads();

    float m3[4], m4[4], m5[4];
    conv_g2<12,  0, 62>(lds, Bpack, b3, p, nth, l, m3);
    conv_g2<16, 12, 61>(lds, Bpack, b4, p, nth, l, m4);
    conv_g2<20, 28, 60>(lds, Bpack, b5, p, nth, l, m5);
    __syncthreads();                          // docs dead beyond this point

    float* feats = (float*)lds;               // [4][384] aliases doc buffer
    if ((l >> 4) == 0) {
        const int lm = l & 15;
        #pragma unroll
        for (int k = 0; k < 4; ++k) {
            const int c = nth * 64 + k * 16 + lm;
            feats[p * 384 +   0 + c] = m3[k];
            feats[p * 384 + 128 + c] = m4[k];
            feats[p * 384 + 256 + c] = m5[k];
        }
    }
    __syncthreads();

    if (t < 128) {
        const float4* wr4 = (const float4*)(fcw + (size_t)t * (3 * CC));
        float a0 = fcb[t], a1 = a0, a2 = a0, a3 = a0;
        for (int f4 = 0; f4 < 96; ++f4) {
            const float4 wv = wr4[f4];
            const float4 x0 = *(const float4*)&feats[0 * 384 + f4 * 4];
            const float4 x1 = *(const float4*)&feats[1 * 384 + f4 * 4];
            const float4 x2 = *(const float4*)&feats[2 * 384 + f4 * 4];
            const float4 x3 = *(const float4*)&feats[3 * 384 + f4 * 4];
            a0 += x0.x * wv.x + x0.y * wv.y + x0.z * wv.z + x0.w * wv.w;
            a1 += x1.x * wv.x + x1.y * wv.y + x1.z * wv.z + x1.w * wv.w;
            a2 += x2.x * wv.x + x2.y * wv.y + x2.z * wv.z + x2.w * wv.w;
            a3 += x3.x * wv.x + x3.y * wv.y + x3.z * wv.z + x3.w * wv.w;
        }
        out[(size_t)(n0 + 0) * EE + t] = a0;
        out[(size_t)(n0 + 1) * EE + t] = a1;
        out[(size_t)(n0 + 2) * EE + t] = a2;
        out[(size_t)(n0 + 3) * EE + t] = a3;
    }
}

// ---------------------------------------------------------------------------
extern "C" void kernel_launch(void* const* d_in, const int* in_sizes, int n_in,
                              void* d_out, int out_size, void* d_ws, size_t ws_size,
                              hipStream_t stream)
{
    const int*   word2news     = (const int*)d_in[0];
    const int*   word2news_len = (const int*)d_in[1];
    const int*   news_words    = (const int*)d_in[2];
    const float* table         = (const float*)d_in[3];
    const float* in_w          = (const float*)d_in[4];
    const float* in_b          = (const float*)d_in[5];
    const float* out_w         = (const float*)d_in[6];
    const float* out_b         = (const float*)d_in[7];
    const float* w3            = (const float*)d_in[8];
    const float* b3            = (const float*)d_in[9];
    const float* w4            = (const float*)d_in[10];
    const float* b4            = (const float*)d_in[11];
    const float* w5            = (const float*)d_in[12];
    const float* b5            = (const float*)d_in[13];
    const float* fcw           = (const float*)d_in[14];
    const float* fcb           = (const float*)d_in[15];

    float* out = (float*)d_out;
    u16* base  = (u16*)d_ws;
    u16* we16  = base;                                   // 2,560,000 u16 (5.12 MB)
    u16* Bpack = base + 2560000;                         //   196,608 u16
    u16* Kn16  = base + 2756608;                         // 1,048,576 u16
    u16* Wn16  = base + 3805184;                         // 1,048,576 u16 (Vn slot)
    u16* Qn16  = base + 4853760;                         // 1,048,576 u16 (11.80 MB)
    const size_t need_qn = (size_t)(4853760 + 1048576) * 2;

    pack_weights<<<48, 256, 0, stream>>>(w3, w4, w5, Bpack);

    if (ws_size >= need_qn) {
        kvqw_proj_kernel<<<NN / 8, 384, 0, stream>>>(table, in_w, in_b,
                                                     out_w, out_b,
                                                     Qn16, Kn16, Wn16);
        word_attn_wn<<<V_WORDS / WPB, 256, 0, stream>>>(
            word2news, word2news_len, Qn16, Kn16, Wn16, we16);
    } else {
        kv_proj_kernel<<<NN / 8, 256, 0, stream>>>(table, in_w, in_b, Kn16, Wn16);
        word_attn_kernel<<<V_WORDS / WPB, 256, 0, stream>>>(
            word2news, word2news_len, table, in_w, in_b, out_w, out_b,
            Kn16, Wn16, we16);
    }

    news_kernel<<<NN / 4, 512, 0, stream>>>(
        news_words, we16, Bpack, b3, b4, b5, fcw, fcb, out);
}

// Round 2
// 375.281 us; speedup vs baseline: 8.1181x; 8.1181x over previous
//
#include <hip/hip_runtime.h>
#include <math.h>

#define V_WORDS 20000
#define MM 32
#define EE 128
#define HH 4
#define DHH 32
#define NN 8192
#define LL 64
#define CC 128

typedef short bf16x8 __attribute__((ext_vector_type(8)));
typedef float f32x4 __attribute__((ext_vector_type(4)));
typedef unsigned short u16;
typedef unsigned int u32;

__device__ __forceinline__ u16 f2bf(float x) {
    u32 u = __float_as_uint(x);
    u32 r = (u + 0x7FFFu + ((u >> 16) & 1u)) >> 16;
    return (u16)r;
}
__device__ __forceinline__ float bflo(u32 u) { return __uint_as_float(u << 16); }
__device__ __forceinline__ float bfhi(u32 u) { return __uint_as_float(u & 0xFFFF0000u); }

// ---------------------------------------------------------------------------
// Kernel 0: pack conv weights into bf16 MFMA B-fragment order (unchanged).
// ---------------------------------------------------------------------------
__global__ __launch_bounds__(256)
void pack_weights(const float* __restrict__ w3,
                  const float* __restrict__ w4,
                  const float* __restrict__ w5,
                  u16* __restrict__ Bpack)
{
    const int s = blockIdx.x;
    const int t = threadIdx.x;
    const int lane = t & 63;

    const float* src;
    int K, sl;
    if (s < 12)      { src = w3; K = 3; sl = s; }
    else if (s < 28) { src = w4; K = 4; sl = s - 12; }
    else             { src = w5; K = 5; sl = s - 28; }
    const int j  = sl >> 2;
    const int e0 = (sl & 3) * 32;

    for (int nt = (t >> 6); nt < 8; nt += 4) {
        const int c = nt * 16 + (lane & 15);
        const int kb = (lane >> 4) * 8;
        u16 vals[8];
        #pragma unroll
        for (int i = 0; i < 8; ++i) {
            const int e = e0 + kb + i;
            vals[i] = f2bf(src[(c * EE + e) * K + j]);
        }
        u16* dst = Bpack + (((size_t)s * 8 + nt) * 64 + lane) * 8;
        *(bf16x8*)dst = *(const bf16x8*)vals;
    }
}

// ---------------------------------------------------------------------------
// Kernel A (fallback, ws too small): Kn/Vn projections (R15 path).
// ---------------------------------------------------------------------------
__global__ __launch_bounds__(256)
void kv_proj_kernel(const float* __restrict__ table,
                    const float* __restrict__ in_w,
                    const float* __restrict__ in_b,
                    u16* __restrict__ Kn16, u16* __restrict__ Vn16)
{
    const int n0 = blockIdx.x * 8;
    const int t = threadIdx.x;
    __shared__ float tbl[8][EE];
    {
        const int r = t >> 5, q4 = (t & 31) * 4;
        *(float4*)&tbl[r][q4] = *(const float4*)&table[(size_t)(n0 + r) * EE + q4];
    }
    __syncthreads();

    const int sel = t >> 7;
    const int i = t & 127;
    const float* w = in_w + (size_t)(sel + 1) * EE * EE + (size_t)i * EE;
    const float bias = in_b[(sel + 1) * EE + i];

    float acc[8];
    #pragma unroll
    for (int r = 0; r < 8; ++r) acc[r] = bias;
    for (int k = 0; k < EE; k += 4) {
        const float4 wv = *(const float4*)&w[k];
        #pragma unroll
        for (int r = 0; r < 8; ++r) {
            acc[r] += tbl[r][k]     * wv.x + tbl[r][k + 1] * wv.y
                    + tbl[r][k + 2] * wv.z + tbl[r][k + 3] * wv.w;
        }
    }
    u16* dst = sel ? Vn16 : Kn16;
    #pragma unroll
    for (int r = 0; r < 8; ++r) dst[(size_t)(n0 + r) * EE + i] = f2bf(acc[r]);
}

// ---------------------------------------------------------------------------
// Kernel A'' (R19): Q/K/W projections over the 8192 distinct news rows.
// ---------------------------------------------------------------------------
__global__ __launch_bounds__(384)
void kvqw_proj_kernel(const float* __restrict__ table,
                      const float* __restrict__ in_w,
                      const float* __restrict__ in_b,
                      const float* __restrict__ out_w,
                      const float* __restrict__ out_b,
                      u16* __restrict__ Qn16,
                      u16* __restrict__ Kn16,
                      u16* __restrict__ Wn16)
{
    const int n0 = blockIdx.x * 8;
    const int t = threadIdx.x;
    __shared__ float tbl[8][EE];
    __shared__ float vsh[8][EE];
    if (t < 256) {
        const int r = t >> 5, q4 = (t & 31) * 4;
        *(float4*)&tbl[r][q4] = *(const float4*)&table[(size_t)(n0 + r) * EE + q4];
    }
    __syncthreads();

    const int sel = t >> 7;                 // 0 = Q, 1 = K, 2 = V
    const int i = t & 127;
    const float* w = in_w + (size_t)sel * EE * EE + (size_t)i * EE;
    const float bias = in_b[sel * EE + i];

    float acc[8];
    #pragma unroll
    for (int r = 0; r < 8; ++r) acc[r] = bias;
    for (int k = 0; k < EE; k += 4) {
        const float4 wv = *(const float4*)&w[k];
        #pragma unroll
        for (int r = 0; r < 8; ++r) {
            acc[r] += tbl[r][k]     * wv.x + tbl[r][k + 1] * wv.y
                    + tbl[r][k + 2] * wv.z + tbl[r][k + 3] * wv.w;
        }
    }
    if (sel == 0) {
        #pragma unroll
        for (int r = 0; r < 8; ++r) Qn16[(size_t)(n0 + r) * EE + i] = f2bf(acc[r]);
    } else if (sel == 1) {
        #pragma unroll
        for (int r = 0; r < 8; ++r) Kn16[(size_t)(n0 + r) * EE + i] = f2bf(acc[r]);
    } else {
        #pragma unroll
        for (int r = 0; r < 8; ++r) vsh[r][i] = acc[r];   // keep V fp32 for phase 2
    }
    __syncthreads();

    // Phase 2: Wn[r][i] = vsh[r] . out_w[i] + out_b[i]
    {
        const int g = t >> 7;
        const int r0 = g, r1 = g + 3, r2 = g + 6;       // r2 == 8 invalid for g==2
        const int r2c = (r2 < 8) ? r2 : 7;
        const float* wr = out_w + (size_t)i * EE;
        const float ob = out_b[i];
        float a0 = ob, a1 = ob, a2 = ob;
        #pragma unroll 4
        for (int k = 0; k < EE; k += 4) {
            const float4 wv = *(const float4*)&wr[k];
            a0 += vsh[r0][k]   * wv.x + vsh[r0][k+1] * wv.y
                + vsh[r0][k+2] * wv.z + vsh[r0][k+3] * wv.w;
            a1 += vsh[r1][k]   * wv.x + vsh[r1][k+1] * wv.y
                + vsh[r1][k+2] * wv.z + vsh[r1][k+3] * wv.w;
            a2 += vsh[r2c][k]   * wv.x + vsh[r2c][k+1] * wv.y
                + vsh[r2c][k+2] * wv.z + vsh[r2c][k+3] * wv.w;
        }
        Wn16[(size_t)(n0 + r0) * EE + i] = f2bf(a0);
        Wn16[(size_t)(n0 + r1) * EE + i] = f2bf(a1);
        if (r2 < 8) Wn16[(size_t)(n0 + r2) * EE + i] = f2bf(a2);
    }
}

// ---------------------------------------------------------------------------
// Kernel B (fallback): per-word attention, R15 path (unchanged).
// ---------------------------------------------------------------------------
#define WPB 8
__global__ __launch_bounds__(256, 3)
void word_attn_kernel(const int* __restrict__ word2news,
                      const int* __restrict__ word2news_len,
                      const float* __restrict__ table,
                      const float* __restrict__ in_w,
                      const float* __restrict__ in_b,
                      const float* __restrict__ out_w,
                      const float* __restrict__ out_b,
                      const u16* __restrict__ Kn16,
                      const u16* __restrict__ Vn16,
                      u16* __restrict__ we16)
{
    const int v0 = blockIdx.x * WPB;
    const int t = threadIdx.x;

    __shared__ int   rows[WPB][MM];
    __shared__ int   lenS[WPB];
    __shared__ float q[WPB][EE];
    __shared__ float qh[WPB][EE];
    __shared__ float attn[WPB][HH][MM];
    __shared__ float osh[WPB][EE];

    {
        const int w = t >> 5, m = t & 31;
        rows[w][m] = word2news[(size_t)(v0 + w) * MM + m];
        if (t < WPB) lenS[t] = word2news_len[v0 + t];
    }
    __syncthreads();

    {
        const int w = t >> 5, d0 = (t & 31) * 4;
        const int L = lenS[w];
        float4 a = {0.f, 0.f, 0.f, 0.f};
        #pragma unroll 4
        for (int m = 0; m < MM; ++m) {
            const float4 x = *(const float4*)&table[(size_t)rows[w][m] * EE + d0];
            if (m < L) { a.x += x.x; a.y += x.y; a.z += x.z; a.w += x.w; }
        }
        const float inv = (L > 0) ? 1.0f / (float)L : 0.0f;
        a.x *= inv; a.y *= inv; a.z *= inv; a.w *= inv;
        *(float4*)&q[w][d0] = a;
    }
    __syncthreads();

    {
        const int g = t >> 7, i = t & 127;
        const float* wr = in_w + (size_t)i * EE;
        float acc[4] = {0.f, 0.f, 0.f, 0.f};
        #pragma unroll 4
        for (int k = 0; k < EE; k += 4) {
            const float4 wv = *(const float4*)&wr[k];
            #pragma unroll
            for (int w4 = 0; w4 < 4; ++w4) {
                const float* qw = q[g * 4 + w4];
                acc[w4] += qw[k] * wv.x + qw[k + 1] * wv.y
                         + qw[k + 2] * wv.z + qw[k + 3] * wv.w;
            }
        }
        const float b = in_b[i];
        #pragma unroll
        for (int w4 = 0; w4 < 4; ++w4) qh[g * 4 + w4][i] = acc[w4] + b;
    }
    __syncthreads();

    {
        const int w = t >> 5, m = t & 31;
        const int L = lenS[w];
        float s[HH] = {-1e9f, -1e9f, -1e9f, -1e9f};
        if (m < L) {
            const uint4* kr = (const uint4*)(Kn16 + (size_t)rows[w][m] * EE);
            #pragma unroll 1
            for (int h = 0; h < HH; ++h) {
                float a = 0.f;
                #pragma unroll
                for (int k8 = 0; k8 < 4; ++k8) {
                    const uint4 u = kr[h * 4 + k8];
                    const float4 q0 = *(const float4*)&qh[w][h * 32 + k8 * 8];
                    const float4 q1 = *(const float4*)&qh[w][h * 32 + k8 * 8 + 4];
                    a += q0.x * bflo(u.x) + q0.y * bfhi(u.x)
                       + q0.z * bflo(u.y) + q0.w * bfhi(u.y)
                       + q1.x * bflo(u.z) + q1.y * bfhi(u.z)
                       + q1.z * bflo(u.w) + q1.w * bfhi(u.w);
                }
                s[h] = a * 0.17677669529663687f;
            }
        }
        #pragma unroll
        for (int h = 0; h < HH; ++h) {
            float mx = s[h];
            #pragma unroll
            for (int off = 16; off > 0; off >>= 1)
                mx = fmaxf(mx, __shfl_xor(mx, off, 32));
            const float ex = expf(s[h] - mx);
            float sum = ex;
            #pragma unroll
            for (int off = 16; off > 0; off >>= 1)
                sum += __shfl_xor(sum, off, 32);
            attn[w][h][m] = ex / sum;
        }
    }
    __syncthreads();

    {
        const int w = t >> 5, d0 = (t & 31) * 4;
        const int h = d0 >> 5;
        float4 a = {0.f, 0.f, 0.f, 0.f};
        #pragma unroll 4
        for (int m = 0; m < MM; ++m) {
            const float aw = attn[w][h][m];
            const u32* vr = (const u32*)(Vn16 + (size_t)rows[w][m] * EE + d0);
            const u32 u0 = vr[0], u1 = vr[1];
            a.x += aw * bflo(u0); a.y += aw * bfhi(u0);
            a.z += aw * bflo(u1); a.w += aw * bfhi(u1);
        }
        *(float4*)&osh[w][d0] = a;
    }
    __syncthreads();

    {
        const int g = t >> 7, i = t & 127;
        const float* wr = out_w + (size_t)i * EE;
        float acc[4] = {0.f, 0.f, 0.f, 0.f};
        #pragma unroll 4
        for (int k = 0; k < EE; k += 4) {
            const float4 wv = *(const float4*)&wr[k];
            #pragma unroll
            for (int w4 = 0; w4 < 4; ++w4) {
                const float* ow = osh[g * 4 + w4];
                acc[w4] += ow[k] * wv.x + ow[k + 1] * wv.y
                         + ow[k + 2] * wv.z + ow[k + 3] * wv.w;
            }
        }
        const float b = out_b[i];
        #pragma unroll
        for (int w4 = 0; w4 < 4; ++w4) {
            const int w = g * 4 + w4;
            we16[(size_t)(v0 + w) * EE + i] =
                (lenS[w] > 0) ? f2bf(acc[w4] + b) : (u16)0;
        }
    }
}

// ---------------------------------------------------------------------------
// Kernel B'' (R21 == R20): per-word attention, fully fused, deep in-flight
// gather loads (Q-mean unroll 8 / 8B loads; score phase prefetches the
// head-pair's 8x uint4 before FMAs; W phase unroll 8 / 8B loads).
// ---------------------------------------------------------------------------
__global__ __launch_bounds__(256, 3)
void word_attn_wn(const int* __restrict__ word2news,
                  const int* __restrict__ word2news_len,
                  const u16* __restrict__ Qn16,
                  const u16* __restrict__ Kn16,
                  const u16* __restrict__ Wn16,
                  u16* __restrict__ we16)
{
    const int v0 = blockIdx.x * WPB;
    const int t = threadIdx.x;

    __shared__ int   rows[WPB][MM];
    __shared__ int   lenS[WPB];
    __shared__ float qh[WPB][EE];
    __shared__ float attn[WPB][HH][MM];

    {
        const int w = t >> 5, m = t & 31;
        rows[w][m] = word2news[(size_t)(v0 + w) * MM + m];
        if (t < WPB) lenS[t] = word2news_len[v0 + t];
    }
    __syncthreads();

    // qh = mean of gathered Qn rows (bias included; exact — weights sum to 1)
    {
        const int w = t >> 5, d0 = (t & 31) * 4;
        const int L = lenS[w];
        float4 a = {0.f, 0.f, 0.f, 0.f};
        #pragma unroll 8
        for (int m = 0; m < MM; ++m) {
            const uint2 u = *(const uint2*)(Qn16 + (size_t)rows[w][m] * EE + d0);
            if (m < L) {
                a.x += bflo(u.x); a.y += bfhi(u.x);
                a.z += bflo(u.y); a.w += bfhi(u.y);
            }
        }
        const float inv = (L > 0) ? 1.0f / (float)L : 0.0f;
        a.x *= inv; a.y *= inv; a.z *= inv; a.w *= inv;
        *(float4*)&qh[w][d0] = a;
    }
    __syncthreads();

    // scores (gather Kn rows) + softmax over m; head-PAIR at a time with the
    // pair's 8 uint4 (128B) prefetched before any FMA -> 8 loads in flight.
    {
        const int w = t >> 5, m = t & 31;
        const int L = lenS[w];
        float s[HH] = {-1e9f, -1e9f, -1e9f, -1e9f};
        if (m < L) {
            const uint4* kr = (const uint4*)(Kn16 + (size_t)rows[w][m] * EE);
            #pragma unroll
            for (int hp = 0; hp < 2; ++hp) {
                uint4 kq[8];
                #pragma unroll
                for (int q8 = 0; q8 < 8; ++q8) kq[q8] = kr[hp * 8 + q8];
                #pragma unroll
                for (int hl = 0; hl < 2; ++hl) {
                    const int h = hp * 2 + hl;
                    float a = 0.f;
                    #pragma unroll
                    for (int k8 = 0; k8 < 4; ++k8) {
                        const uint4 u = kq[hl * 4 + k8];
                        const float4 q0 = *(const float4*)&qh[w][h * 32 + k8 * 8];
                        const float4 q1 = *(const float4*)&qh[w][h * 32 + k8 * 8 + 4];
                        a += q0.x * bflo(u.x) + q0.y * bfhi(u.x)
                           + q0.z * bflo(u.y) + q0.w * bfhi(u.y)
                           + q1.x * bflo(u.z) + q1.y * bfhi(u.z)
                           + q1.z * bflo(u.w) + q1.w * bfhi(u.w);
                    }
                    s[h] = a * 0.17677669529663687f;
                }
            }
        }
        #pragma unroll
        for (int h = 0; h < HH; ++h) {
            float mx = s[h];
            #pragma unroll
            for (int off = 16; off > 0; off >>= 1)
                mx = fmaxf(mx, __shfl_xor(mx, off, 32));
            const float ex = expf(s[h] - mx);      // masked lanes underflow to 0
            float sum = ex;
            #pragma unroll
            for (int off = 16; off > 0; off >>= 1)
                sum += __shfl_xor(sum, off, 32);
            attn[w][h][m] = ex / sum;
        }
    }
    __syncthreads();

    // we = sum_m attn_m * Wn[rows[m]]  (out-proj + bias pre-folded into Wn)
    {
        const int w = t >> 5, d0 = (t & 31) * 4;
        const int h = d0 >> 5;
        const int L = lenS[w];
        float4 a = {0.f, 0.f, 0.f, 0.f};
        #pragma unroll 8
        for (int m = 0; m < MM; ++m) {
            const float aw = attn[w][h][m];
            const uint2 u = *(const uint2*)(Wn16 + (size_t)rows[w][m] * EE + d0);
            a.x += aw * bflo(u.x); a.y += aw * bfhi(u.x);
            a.z += aw * bflo(u.y); a.w += aw * bfhi(u.y);
        }
        u32 lo = 0u, hi = 0u;
        if (L > 0) {
            lo = (u32)f2bf(a.x) | ((u32)f2bf(a.y) << 16);
            hi = (u32)f2bf(a.z) | ((u32)f2bf(a.w) << 16);
        }
        u32* dst = (u32*)(we16 + (size_t)(v0 + w) * EE + d0);
        dst[0] = lo; dst[1] = hi;
    }
}

// ---------------------------------------------------------------------------
// Kernel 2: implicit-GEMM conv — REVERTED to R16/R18 MEASURED OPTIMUM
// (#pragma unroll 2). R20's full unroll spilled: the unrolled body keeps
// 48-80 global B-fragment loads live -> regalloc spill to scratch ->
// FETCH 3.8GB / WRITE 7.2GB of spill traffic, 214us -> 2900us. Unroll 2
// keeps the live set at 8 loads + 64 AGPR acc, zero spill (measured).
// ---------------------------------------------------------------------------
#define DSTRIDE 136              // u16 per doc row (16B-aligned, 68 words)
#define DOCSZ   (68 * DSTRIDE)   // u16 per doc (64 data rows + 4 zero rows)

template<int NSL, int SBASE, int NP>
__device__ __forceinline__ void conv_g2(const u16* __restrict__ lds,
                                        const u16* __restrict__ Bpack,
                                        const float* __restrict__ bk,
                                        int p, int nth, int l,
                                        float (&mxout)[4])
{
    f32x4 acc[4][4];
    #pragma unroll
    for (int mt = 0; mt < 4; ++mt)
        #pragma unroll
        for (int k = 0; k < 4; ++k)
            acc[mt][k] = (f32x4){0.f, 0.f, 0.f, 0.f};

    const int lm = l & 15;
    const int g  = l >> 4;
    const u16* bbase = Bpack + ((size_t)SBASE * 8 + nth * 4) * 512 + l * 8;
    const u16* abase = lds + (size_t)p * DOCSZ;

    #pragma unroll 2
    for (int s = 0; s < NSL; ++s) {
        const int j  = s >> 2;
        const int e0 = (s & 3) * 32;

        bf16x8 b[4];
        #pragma unroll
        for (int k = 0; k < 4; ++k)
            b[k] = *(const bf16x8*)(bbase + s * 4096 + k * 512);

        const u16* arow = abase + (lm + j) * DSTRIDE + e0 + g * 8;
        bf16x8 a[4];
        #pragma unroll
        for (int mt = 0; mt < 4; ++mt)
            a[mt] = *(const bf16x8*)(arow + mt * (16 * DSTRIDE));

        #pragma unroll
        for (int mt = 0; mt < 4; ++mt)
            #pragma unroll
            for (int k = 0; k < 4; ++k)
                acc[mt][k] = __builtin_amdgcn_mfma_f32_16x16x32_bf16(a[mt], b[k], acc[mt][k], 0, 0, 0);
    }

    #pragma unroll
    for (int k = 0; k < 4; ++k) {
        const int c = nth * 64 + k * 16 + lm;
        const float bias = bk[c];
        float mx = 0.0f;                     // relu output >= 0
        #pragma unroll
        for (int mt = 0; mt < 4; ++mt) {
            #pragma unroll
            for (int r = 0; r < 4; ++r) {
                const int pos = 16 * mt + g * 4 + r;
                const float y = fmaxf(acc[mt][k][r] + bias, 0.0f);
                if (pos < NP) mx = fmaxf(mx, y);
            }
        }
        mx = fmaxf(mx, __shfl_xor(mx, 16));
        mx = fmaxf(mx, __shfl_xor(mx, 32));
        mxout[k] = mx;
    }
}

__global__ __launch_bounds__(512, 4)
void news_kernel(const int* __restrict__ news_words,
                 const u16* __restrict__ we16,
                 const u16* __restrict__ Bpack,
                 const float* __restrict__ b3,
                 const float* __restrict__ b4,
                 const float* __restrict__ b5,
                 const float* __restrict__ fcw, const float* __restrict__ fcb,
                 float* __restrict__ out)
{
    const int n0 = blockIdx.x * 4;
    const int t = threadIdx.x;
    const int w = t >> 6, l = t & 63;
    const int p = w >> 1, nth = w & 1;

    __shared__ u16 lds[4 * DOCSZ];           // 73,984 B; feats alias after convs
    __shared__ int rows[4 * LL];

    if (t < 4 * LL) rows[t] = news_words[(size_t)n0 * LL + t];
    __syncthreads();

    {
        const uint4* weU = (const uint4*)we16;     // 16 uint4 per doc row
        uint4* ldsU = (uint4*)lds;                 // doc stride 1156 uint4
        for (int idx = t; idx < 4096; idx += 512) {
            const int d = idx >> 10, rem = idx & 1023;
            const int row = rem >> 4, c4 = rem & 15;
            ldsU[d * 1156 + row * 17 + c4] = weU[(size_t)rows[d * 64 + row] * 16 + c4];
        }
        if (t < 256) {                             // 4 docs x 4 pad rows x 16
            const int d = t >> 6, rem = t & 63;
            const int row = 64 + (rem >> 4), c4 = rem & 15;
            ldsU[d * 1156 + row * 17 + c4] = (uint4){0u, 0u, 0u, 0u};
        }
    }
    __syncthreads();

    float m3[4], m4[4], m5[4];
    conv_g2<12,  0, 62>(lds, Bpack, b3, p, nth, l, m3);
    conv_g2<16, 12, 61>(lds, Bpack, b4, p, nth, l, m4);
    conv_g2<20, 28, 60>(lds, Bpack, b5, p, nth, l, m5);
    __syncthreads();                          // docs dead beyond this point

    float* feats = (float*)lds;               // [4][384] aliases doc buffer
    if ((l >> 4) == 0) {
        const int lm = l & 15;
        #pragma unroll
        for (int k = 0; k < 4; ++k) {
            const int c = nth * 64 + k * 16 + lm;
            feats[p * 384 +   0 + c] = m3[k];
            feats[p * 384 + 128 + c] = m4[k];
            feats[p * 384 + 256 + c] = m5[k];
        }
    }
    __syncthreads();

    if (t < 128) {
        const float4* wr4 = (const float4*)(fcw + (size_t)t * (3 * CC));
        float a0 = fcb[t], a1 = a0, a2 = a0, a3 = a0;
        for (int f4 = 0; f4 < 96; ++f4) {
            const float4 wv = wr4[f4];
            const float4 x0 = *(const float4*)&feats[0 * 384 + f4 * 4];
            const float4 x1 = *(const float4*)&feats[1 * 384 + f4 * 4];
            const float4 x2 = *(const float4*)&feats[2 * 384 + f4 * 4];
            const float4 x3 = *(const float4*)&feats[3 * 384 + f4 * 4];
            a0 += x0.x * wv.x + x0.y * wv.y + x0.z * wv.z + x0.w * wv.w;
            a1 += x1.x * wv.x + x1.y * wv.y + x1.z * wv.z + x1.w * wv.w;
            a2 += x2.x * wv.x + x2.y * wv.y + x2.z * wv.z + x2.w * wv.w;
            a3 += x3.x * wv.x + x3.y * wv.y + x3.z * wv.z + x3.w * wv.w;
        }
        out[(size_t)(n0 + 0) * EE + t] = a0;
        out[(size_t)(n0 + 1) * EE + t] = a1;
        out[(size_t)(n0 + 2) * EE + t] = a2;
        out[(size_t)(n0 + 3) * EE + t] = a3;
    }
}

// ---------------------------------------------------------------------------
extern "C" void kernel_launch(void* const* d_in, const int* in_sizes, int n_in,
                              void* d_out, int out_size, void* d_ws, size_t ws_size,
                              hipStream_t stream)
{
    const int*   word2news     = (const int*)d_in[0];
    const int*   word2news_len = (const int*)d_in[1];
    const int*   news_words    = (const int*)d_in[2];
    const float* table         = (const float*)d_in[3];
    const float* in_w          = (const float*)d_in[4];
    const float* in_b          = (const float*)d_in[5];
    const float* out_w         = (const float*)d_in[6];
    const float* out_b         = (const float*)d_in[7];
    const float* w3            = (const float*)d_in[8];
    const float* b3            = (const float*)d_in[9];
    const float* w4            = (const float*)d_in[10];
    const float* b4            = (const float*)d_in[11];
    const float* w5            = (const float*)d_in[12];
    const float* b5            = (const float*)d_in[13];
    const float* fcw           = (const float*)d_in[14];
    const float* fcb           = (const float*)d_in[15];

    float* out = (float*)d_out;
    u16* base  = (u16*)d_ws;
    u16* we16  = base;                                   // 2,560,000 u16 (5.12 MB)
    u16* Bpack = base + 2560000;                         //   196,608 u16
    u16* Kn16  = base + 2756608;                         // 1,048,576 u16
    u16* Wn16  = base + 3805184;                         // 1,048,576 u16 (Vn slot)
    u16* Qn16  = base + 4853760;                         // 1,048,576 u16 (11.80 MB)
    const size_t need_qn = (size_t)(4853760 + 1048576) * 2;

    pack_weights<<<48, 256, 0, stream>>>(w3, w4, w5, Bpack);

    if (ws_size >= need_qn) {
        kvqw_proj_kernel<<<NN / 8, 384, 0, stream>>>(table, in_w, in_b,
                                                     out_w, out_b,
                                                     Qn16, Kn16, Wn16);
        word_attn_wn<<<V_WORDS / WPB, 256, 0, stream>>>(
            word2news, word2news_len, Qn16, Kn16, Wn16, we16);
    } else {
        kv_proj_kernel<<<NN / 8, 256, 0, stream>>>(table, in_w, in_b, Kn16, Wn16);
        word_attn_kernel<<<V_WORDS / WPB, 256, 0, stream>>>(
            word2news, word2news_len, table, in_w, in_b, out_w, out_b,
            Kn16, Wn16, we16);
    }

    news_kernel<<<NN / 4, 512, 0, stream>>>(
        news_words, we16, Bpack, b3, b4, b5, fcw, fcb, out);
}

// Round 3
// 364.460 us; speedup vs baseline: 8.3591x; 1.0297x over previous
//
#include <hip/hip_runtime.h>
#include <math.h>

#define V_WORDS 20000
#define MM 32
#define EE 128
#define HH 4
#define DHH 32
#define NN 8192
#define LL 64
#define CC 128

typedef short bf16x8 __attribute__((ext_vector_type(8)));
typedef float f32x4 __attribute__((ext_vector_type(4)));
typedef unsigned short u16;
typedef unsigned int u32;

__device__ __forceinline__ u16 f2bf(float x) {
    u32 u = __float_as_uint(x);
    u32 r = (u + 0x7FFFu + ((u >> 16) & 1u)) >> 16;
    return (u16)r;
}
__device__ __forceinline__ float bflo(u32 u) { return __uint_as_float(u << 16); }
__device__ __forceinline__ float bfhi(u32 u) { return __uint_as_float(u & 0xFFFF0000u); }

// bf16 pair dot-product: 1 VALU op on gfx950 (v_dot2_f32_bf16) vs 6 for the
// unpack+fma fallback. Guarded: falls back to exact-equivalent f32 math.
#if defined(__has_builtin)
#  if __has_builtin(__builtin_amdgcn_fdot2_f32_bf16)
#    define USE_BF16_DOT2 1
#  endif
#endif
#ifdef USE_BF16_DOT2
typedef __bf16 v2bf __attribute__((ext_vector_type(2)));
#endif

__device__ __forceinline__ float dot2bf(u32 a, u32 b, float c) {
#ifdef USE_BF16_DOT2
    return __builtin_amdgcn_fdot2_f32_bf16(
        __builtin_bit_cast(v2bf, a), __builtin_bit_cast(v2bf, b), c, false);
#else
    return c + bflo(a) * bflo(b) + bfhi(a) * bfhi(b);
#endif
}

// ---------------------------------------------------------------------------
// Kernel 0: pack conv weights into bf16 MFMA B-fragment order (unchanged).
// ---------------------------------------------------------------------------
__global__ __launch_bounds__(256)
void pack_weights(const float* __restrict__ w3,
                  const float* __restrict__ w4,
                  const float* __restrict__ w5,
                  u16* __restrict__ Bpack)
{
    const int s = blockIdx.x;
    const int t = threadIdx.x;
    const int lane = t & 63;

    const float* src;
    int K, sl;
    if (s < 12)      { src = w3; K = 3; sl = s; }
    else if (s < 28) { src = w4; K = 4; sl = s - 12; }
    else             { src = w5; K = 5; sl = s - 28; }
    const int j  = sl >> 2;
    const int e0 = (sl & 3) * 32;

    for (int nt = (t >> 6); nt < 8; nt += 4) {
        const int c = nt * 16 + (lane & 15);
        const int kb = (lane >> 4) * 8;
        u16 vals[8];
        #pragma unroll
        for (int i = 0; i < 8; ++i) {
            const int e = e0 + kb + i;
            vals[i] = f2bf(src[(c * EE + e) * K + j]);
        }
        u16* dst = Bpack + (((size_t)s * 8 + nt) * 64 + lane) * 8;
        *(bf16x8*)dst = *(const bf16x8*)vals;
    }
}

// ---------------------------------------------------------------------------
// Kernel A (fallback, ws too small): Kn/Vn projections (R15 path).
// ---------------------------------------------------------------------------
__global__ __launch_bounds__(256)
void kv_proj_kernel(const float* __restrict__ table,
                    const float* __restrict__ in_w,
                    const float* __restrict__ in_b,
                    u16* __restrict__ Kn16, u16* __restrict__ Vn16)
{
    const int n0 = blockIdx.x * 8;
    const int t = threadIdx.x;
    __shared__ float tbl[8][EE];
    {
        const int r = t >> 5, q4 = (t & 31) * 4;
        *(float4*)&tbl[r][q4] = *(const float4*)&table[(size_t)(n0 + r) * EE + q4];
    }
    __syncthreads();

    const int sel = t >> 7;
    const int i = t & 127;
    const float* w = in_w + (size_t)(sel + 1) * EE * EE + (size_t)i * EE;
    const float bias = in_b[(sel + 1) * EE + i];

    float acc[8];
    #pragma unroll
    for (int r = 0; r < 8; ++r) acc[r] = bias;
    for (int k = 0; k < EE; k += 4) {
        const float4 wv = *(const float4*)&w[k];
        #pragma unroll
        for (int r = 0; r < 8; ++r) {
            acc[r] += tbl[r][k]     * wv.x + tbl[r][k + 1] * wv.y
                    + tbl[r][k + 2] * wv.z + tbl[r][k + 3] * wv.w;
        }
    }
    u16* dst = sel ? Vn16 : Kn16;
    #pragma unroll
    for (int r = 0; r < 8; ++r) dst[(size_t)(n0 + r) * EE + i] = f2bf(acc[r]);
}

// ---------------------------------------------------------------------------
// Kernel A'' (R19): Q/K/W projections over the 8192 distinct news rows.
// ---------------------------------------------------------------------------
__global__ __launch_bounds__(384)
void kvqw_proj_kernel(const float* __restrict__ table,
                      const float* __restrict__ in_w,
                      const float* __restrict__ in_b,
                      const float* __restrict__ out_w,
                      const float* __restrict__ out_b,
                      u16* __restrict__ Qn16,
                      u16* __restrict__ Kn16,
                      u16* __restrict__ Wn16)
{
    const int n0 = blockIdx.x * 8;
    const int t = threadIdx.x;
    __shared__ float tbl[8][EE];
    __shared__ float vsh[8][EE];
    if (t < 256) {
        const int r = t >> 5, q4 = (t & 31) * 4;
        *(float4*)&tbl[r][q4] = *(const float4*)&table[(size_t)(n0 + r) * EE + q4];
    }
    __syncthreads();

    const int sel = t >> 7;                 // 0 = Q, 1 = K, 2 = V
    const int i = t & 127;
    const float* w = in_w + (size_t)sel * EE * EE + (size_t)i * EE;
    const float bias = in_b[sel * EE + i];

    float acc[8];
    #pragma unroll
    for (int r = 0; r < 8; ++r) acc[r] = bias;
    for (int k = 0; k < EE; k += 4) {
        const float4 wv = *(const float4*)&w[k];
        #pragma unroll
        for (int r = 0; r < 8; ++r) {
            acc[r] += tbl[r][k]     * wv.x + tbl[r][k + 1] * wv.y
                    + tbl[r][k + 2] * wv.z + tbl[r][k + 3] * wv.w;
        }
    }
    if (sel == 0) {
        #pragma unroll
        for (int r = 0; r < 8; ++r) Qn16[(size_t)(n0 + r) * EE + i] = f2bf(acc[r]);
    } else if (sel == 1) {
        #pragma unroll
        for (int r = 0; r < 8; ++r) Kn16[(size_t)(n0 + r) * EE + i] = f2bf(acc[r]);
    } else {
        #pragma unroll
        for (int r = 0; r < 8; ++r) vsh[r][i] = acc[r];   // keep V fp32 for phase 2
    }
    __syncthreads();

    // Phase 2: Wn[r][i] = vsh[r] . out_w[i] + out_b[i]
    {
        const int g = t >> 7;
        const int r0 = g, r1 = g + 3, r2 = g + 6;       // r2 == 8 invalid for g==2
        const int r2c = (r2 < 8) ? r2 : 7;
        const float* wr = out_w + (size_t)i * EE;
        const float ob = out_b[i];
        float a0 = ob, a1 = ob, a2 = ob;
        #pragma unroll 4
        for (int k = 0; k < EE; k += 4) {
            const float4 wv = *(const float4*)&wr[k];
            a0 += vsh[r0][k]   * wv.x + vsh[r0][k+1] * wv.y
                + vsh[r0][k+2] * wv.z + vsh[r0][k+3] * wv.w;
            a1 += vsh[r1][k]   * wv.x + vsh[r1][k+1] * wv.y
                + vsh[r1][k+2] * wv.z + vsh[r1][k+3] * wv.w;
            a2 += vsh[r2c][k]   * wv.x + vsh[r2c][k+1] * wv.y
                + vsh[r2c][k+2] * wv.z + vsh[r2c][k+3] * wv.w;
        }
        Wn16[(size_t)(n0 + r0) * EE + i] = f2bf(a0);
        Wn16[(size_t)(n0 + r1) * EE + i] = f2bf(a1);
        if (r2 < 8) Wn16[(size_t)(n0 + r2) * EE + i] = f2bf(a2);
    }
}

// ---------------------------------------------------------------------------
// Kernel B (fallback): per-word attention, R15 path (unchanged).
// ---------------------------------------------------------------------------
#define WPB 8
__global__ __launch_bounds__(256, 3)
void word_attn_kernel(const int* __restrict__ word2news,
                      const int* __restrict__ word2news_len,
                      const float* __restrict__ table,
                      const float* __restrict__ in_w,
                      const float* __restrict__ in_b,
                      const float* __restrict__ out_w,
                      const float* __restrict__ out_b,
                      const u16* __restrict__ Kn16,
                      const u16* __restrict__ Vn16,
                      u16* __restrict__ we16)
{
    const int v0 = blockIdx.x * WPB;
    const int t = threadIdx.x;

    __shared__ int   rows[WPB][MM];
    __shared__ int   lenS[WPB];
    __shared__ float q[WPB][EE];
    __shared__ float qh[WPB][EE];
    __shared__ float attn[WPB][HH][MM];
    __shared__ float osh[WPB][EE];

    {
        const int w = t >> 5, m = t & 31;
        rows[w][m] = word2news[(size_t)(v0 + w) * MM + m];
        if (t < WPB) lenS[t] = word2news_len[v0 + t];
    }
    __syncthreads();

    {
        const int w = t >> 5, d0 = (t & 31) * 4;
        const int L = lenS[w];
        float4 a = {0.f, 0.f, 0.f, 0.f};
        #pragma unroll 4
        for (int m = 0; m < MM; ++m) {
            const float4 x = *(const float4*)&table[(size_t)rows[w][m] * EE + d0];
            if (m < L) { a.x += x.x; a.y += x.y; a.z += x.z; a.w += x.w; }
        }
        const float inv = (L > 0) ? 1.0f / (float)L : 0.0f;
        a.x *= inv; a.y *= inv; a.z *= inv; a.w *= inv;
        *(float4*)&q[w][d0] = a;
    }
    __syncthreads();

    {
        const int g = t >> 7, i = t & 127;
        const float* wr = in_w + (size_t)i * EE;
        float acc[4] = {0.f, 0.f, 0.f, 0.f};
        #pragma unroll 4
        for (int k = 0; k < EE; k += 4) {
            const float4 wv = *(const float4*)&wr[k];
            #pragma unroll
            for (int w4 = 0; w4 < 4; ++w4) {
                const float* qw = q[g * 4 + w4];
                acc[w4] += qw[k] * wv.x + qw[k + 1] * wv.y
                         + qw[k + 2] * wv.z + qw[k + 3] * wv.w;
            }
        }
        const float b = in_b[i];
        #pragma unroll
        for (int w4 = 0; w4 < 4; ++w4) qh[g * 4 + w4][i] = acc[w4] + b;
    }
    __syncthreads();

    {
        const int w = t >> 5, m = t & 31;
        const int L = lenS[w];
        float s[HH] = {-1e9f, -1e9f, -1e9f, -1e9f};
        if (m < L) {
            const uint4* kr = (const uint4*)(Kn16 + (size_t)rows[w][m] * EE);
            #pragma unroll 1
            for (int h = 0; h < HH; ++h) {
                float a = 0.f;
                #pragma unroll
                for (int k8 = 0; k8 < 4; ++k8) {
                    const uint4 u = kr[h * 4 + k8];
                    const float4 q0 = *(const float4*)&qh[w][h * 32 + k8 * 8];
                    const float4 q1 = *(const float4*)&qh[w][h * 32 + k8 * 8 + 4];
                    a += q0.x * bflo(u.x) + q0.y * bfhi(u.x)
                       + q0.z * bflo(u.y) + q0.w * bfhi(u.y)
                       + q1.x * bflo(u.z) + q1.y * bfhi(u.z)
                       + q1.z * bflo(u.w) + q1.w * bfhi(u.w);
                }
                s[h] = a * 0.17677669529663687f;
            }
        }
        #pragma unroll
        for (int h = 0; h < HH; ++h) {
            float mx = s[h];
            #pragma unroll
            for (int off = 16; off > 0; off >>= 1)
                mx = fmaxf(mx, __shfl_xor(mx, off, 32));
            const float ex = expf(s[h] - mx);
            float sum = ex;
            #pragma unroll
            for (int off = 16; off > 0; off >>= 1)
                sum += __shfl_xor(sum, off, 32);
            attn[w][h][m] = ex / sum;
        }
    }
    __syncthreads();

    {
        const int w = t >> 5, d0 = (t & 31) * 4;
        const int h = d0 >> 5;
        float4 a = {0.f, 0.f, 0.f, 0.f};
        #pragma unroll 4
        for (int m = 0; m < MM; ++m) {
            const float aw = attn[w][h][m];
            const u32* vr = (const u32*)(Vn16 + (size_t)rows[w][m] * EE + d0);
            const u32 u0 = vr[0], u1 = vr[1];
            a.x += aw * bflo(u0); a.y += aw * bfhi(u0);
            a.z += aw * bflo(u1); a.w += aw * bfhi(u1);
        }
        *(float4*)&osh[w][d0] = a;
    }
    __syncthreads();

    {
        const int g = t >> 7, i = t & 127;
        const float* wr = out_w + (size_t)i * EE;
        float acc[4] = {0.f, 0.f, 0.f, 0.f};
        #pragma unroll 4
        for (int k = 0; k < EE; k += 4) {
            const float4 wv = *(const float4*)&wr[k];
            #pragma unroll
            for (int w4 = 0; w4 < 4; ++w4) {
                const float* ow = osh[g * 4 + w4];
                acc[w4] += ow[k] * wv.x + ow[k + 1] * wv.y
                         + ow[k + 2] * wv.z + ow[k + 3] * wv.w;
            }
        }
        const float b = out_b[i];
        #pragma unroll
        for (int w4 = 0; w4 < 4; ++w4) {
            const int w = g * 4 + w4;
            we16[(size_t)(v0 + w) * EE + i] =
                (lenS[w] > 0) ? f2bf(acc[w4] + b) : (u16)0;
        }
    }
}

// ---------------------------------------------------------------------------
// Kernel B'' (R22): per-word attention, fully fused. R22 changes (this is a
// gather-latency + VALU-bound kernel, proven responsive in R21):
//  1. Q-mean and Wn phases loop to L (wave-uniform word2news_len) instead of
//     MM=32 — avg len ~15.5, so ~2x less gather traffic + VALU there. Exact:
//     masked Q adds were skipped anyway; attn[m>=L] is exactly 0.
//  2. qh stored as packed bf16 pairs (u32) in LDS: halves score-phase qh
//     LDS reads (b128 gives 4 pairs) at the cost of one extra bf16 rounding.
//  3. Score inner product via v_dot2_f32_bf16 (1 VALU/pair vs 2 unpack+2 fma),
//     guarded by __has_builtin with an exact fallback.
// ---------------------------------------------------------------------------
__global__ __launch_bounds__(256, 3)
void word_attn_wn(const int* __restrict__ word2news,
                  const int* __restrict__ word2news_len,
                  const u16* __restrict__ Qn16,
                  const u16* __restrict__ Kn16,
                  const u16* __restrict__ Wn16,
                  u16* __restrict__ we16)
{
    const int v0 = blockIdx.x * WPB;
    const int t = threadIdx.x;

    __shared__ int   rows[WPB][MM];
    __shared__ int   lenS[WPB];
    __shared__ __align__(16) u32 qhp[WPB][EE / 2];   // bf16-pair packed query
    __shared__ float attn[WPB][HH][MM];

    {
        const int w = t >> 5, m = t & 31;
        rows[w][m] = word2news[(size_t)(v0 + w) * MM + m];
        if (t < WPB) lenS[t] = word2news_len[v0 + t];
    }
    __syncthreads();

    // qh = mean of gathered Qn rows (bias included; exact — weights sum to 1).
    // Loop to L only (uniform per 32-lane warp); pack result as bf16 pairs.
    {
        const int w = t >> 5, d0 = (t & 31) * 4;
        const int L = lenS[w];
        float4 a = {0.f, 0.f, 0.f, 0.f};
        #pragma unroll 4
        for (int m = 0; m < L; ++m) {
            const uint2 u = *(const uint2*)(Qn16 + (size_t)rows[w][m] * EE + d0);
            a.x += bflo(u.x); a.y += bfhi(u.x);
            a.z += bflo(u.y); a.w += bfhi(u.y);
        }
        const float inv = (L > 0) ? 1.0f / (float)L : 0.0f;
        a.x *= inv; a.y *= inv; a.z *= inv; a.w *= inv;
        qhp[w][(d0 >> 1) + 0] = (u32)f2bf(a.x) | ((u32)f2bf(a.y) << 16);
        qhp[w][(d0 >> 1) + 1] = (u32)f2bf(a.z) | ((u32)f2bf(a.w) << 16);
    }
    __syncthreads();

    // scores (gather Kn rows) + softmax over m; head-PAIR at a time with the
    // pair's 8 uint4 (128B) prefetched before any dot -> 8 loads in flight.
    {
        const int w = t >> 5, m = t & 31;
        const int L = lenS[w];
        float s[HH] = {-1e9f, -1e9f, -1e9f, -1e9f};
        if (m < L) {
            const uint4* kr = (const uint4*)(Kn16 + (size_t)rows[w][m] * EE);
            const u32* qp = qhp[w];
            #pragma unroll
            for (int hp = 0; hp < 2; ++hp) {
                uint4 kq[8];
                #pragma unroll
                for (int q8 = 0; q8 < 8; ++q8) kq[q8] = kr[hp * 8 + q8];
                #pragma unroll
                for (int hl = 0; hl < 2; ++hl) {
                    const int h = hp * 2 + hl;
                    float a = 0.f;
                    #pragma unroll
                    for (int k8 = 0; k8 < 4; ++k8) {
                        const uint4 u  = kq[hl * 4 + k8];
                        const uint4 qq = *(const uint4*)&qp[h * 16 + k8 * 4];
                        a = dot2bf(u.x, qq.x, a);
                        a = dot2bf(u.y, qq.y, a);
                        a = dot2bf(u.z, qq.z, a);
                        a = dot2bf(u.w, qq.w, a);
                    }
                    s[h] = a * 0.17677669529663687f;
                }
            }
        }
        #pragma unroll
        for (int h = 0; h < HH; ++h) {
            float mx = s[h];
            #pragma unroll
            for (int off = 16; off > 0; off >>= 1)
                mx = fmaxf(mx, __shfl_xor(mx, off, 32));
            const float ex = expf(s[h] - mx);      // masked lanes underflow to 0
            float sum = ex;
            #pragma unroll
            for (int off = 16; off > 0; off >>= 1)
                sum += __shfl_xor(sum, off, 32);
            attn[w][h][m] = ex / sum;
        }
    }
    __syncthreads();

    // we = sum_{m<L} attn_m * Wn[rows[m]]  (out-proj + bias pre-folded into
    // Wn; attn==0 exactly for m>=L so the truncation is exact).
    {
        const int w = t >> 5, d0 = (t & 31) * 4;
        const int h = d0 >> 5;
        const int L = lenS[w];
        float4 a = {0.f, 0.f, 0.f, 0.f};
        #pragma unroll 4
        for (int m = 0; m < L; ++m) {
            const float aw = attn[w][h][m];
            const uint2 u = *(const uint2*)(Wn16 + (size_t)rows[w][m] * EE + d0);
            a.x += aw * bflo(u.x); a.y += aw * bfhi(u.x);
            a.z += aw * bflo(u.y); a.w += aw * bfhi(u.y);
        }
        u32 lo = 0u, hi = 0u;
        if (L > 0) {
            lo = (u32)f2bf(a.x) | ((u32)f2bf(a.y) << 16);
            hi = (u32)f2bf(a.z) | ((u32)f2bf(a.w) << 16);
        }
        u32* dst = (u32*)(we16 + (size_t)(v0 + w) * EE + d0);
        dst[0] = lo; dst[1] = hi;
    }
}

// ---------------------------------------------------------------------------
// Kernel 2: implicit-GEMM conv — R16/R18 MEASURED OPTIMUM, unchanged.
// (#pragma unroll 2; full unroll spills — R20 measured 14x regression.)
// ---------------------------------------------------------------------------
#define DSTRIDE 136              // u16 per doc row (16B-aligned, 68 words)
#define DOCSZ   (68 * DSTRIDE)   // u16 per doc (64 data rows + 4 zero rows)

template<int NSL, int SBASE, int NP>
__device__ __forceinline__ void conv_g2(const u16* __restrict__ lds,
                                        const u16* __restrict__ Bpack,
                                        const float* __restrict__ bk,
                                        int p, int nth, int l,
                                        float (&mxout)[4])
{
    f32x4 acc[4][4];
    #pragma unroll
    for (int mt = 0; mt < 4; ++mt)
        #pragma unroll
        for (int k = 0; k < 4; ++k)
            acc[mt][k] = (f32x4){0.f, 0.f, 0.f, 0.f};

    const int lm = l & 15;
    const int g  = l >> 4;
    const u16* bbase = Bpack + ((size_t)SBASE * 8 + nth * 4) * 512 + l * 8;
    const u16* abase = lds + (size_t)p * DOCSZ;

    #pragma unroll 2
    for (int s = 0; s < NSL; ++s) {
        const int j  = s >> 2;
        const int e0 = (s & 3) * 32;

        bf16x8 b[4];
        #pragma unroll
        for (int k = 0; k < 4; ++k)
            b[k] = *(const bf16x8*)(bbase + s * 4096 + k * 512);

        const u16* arow = abase + (lm + j) * DSTRIDE + e0 + g * 8;
        bf16x8 a[4];
        #pragma unroll
        for (int mt = 0; mt < 4; ++mt)
            a[mt] = *(const bf16x8*)(arow + mt * (16 * DSTRIDE));

        #pragma unroll
        for (int mt = 0; mt < 4; ++mt)
            #pragma unroll
            for (int k = 0; k < 4; ++k)
                acc[mt][k] = __builtin_amdgcn_mfma_f32_16x16x32_bf16(a[mt], b[k], acc[mt][k], 0, 0, 0);
    }

    #pragma unroll
    for (int k = 0; k < 4; ++k) {
        const int c = nth * 64 + k * 16 + lm;
        const float bias = bk[c];
        float mx = 0.0f;                     // relu output >= 0
        #pragma unroll
        for (int mt = 0; mt < 4; ++mt) {
            #pragma unroll
            for (int r = 0; r < 4; ++r) {
                const int pos = 16 * mt + g * 4 + r;
                const float y = fmaxf(acc[mt][k][r] + bias, 0.0f);
                if (pos < NP) mx = fmaxf(mx, y);
            }
        }
        mx = fmaxf(mx, __shfl_xor(mx, 16));
        mx = fmaxf(mx, __shfl_xor(mx, 32));
        mxout[k] = mx;
    }
}

__global__ __launch_bounds__(512, 4)
void news_kernel(const int* __restrict__ news_words,
                 const u16* __restrict__ we16,
                 const u16* __restrict__ Bpack,
                 const float* __restrict__ b3,
                 const float* __restrict__ b4,
                 const float* __restrict__ b5,
                 const float* __restrict__ fcw, const float* __restrict__ fcb,
                 float* __restrict__ out)
{
    const int n0 = blockIdx.x * 4;
    const int t = threadIdx.x;
    const int w = t >> 6, l = t & 63;
    const int p = w >> 1, nth = w & 1;

    __shared__ u16 lds[4 * DOCSZ];           // 73,984 B; feats alias after convs
    __shared__ int rows[4 * LL];

    if (t < 4 * LL) rows[t] = news_words[(size_t)n0 * LL + t];
    __syncthreads();

    {
        const uint4* weU = (const uint4*)we16;     // 16 uint4 per doc row
        uint4* ldsU = (uint4*)lds;                 // doc stride 1156 uint4
        for (int idx = t; idx < 4096; idx += 512) {
            const int d = idx >> 10, rem = idx & 1023;
            const int row = rem >> 4, c4 = rem & 15;
            ldsU[d * 1156 + row * 17 + c4] = weU[(size_t)rows[d * 64 + row] * 16 + c4];
        }
        if (t < 256) {                             // 4 docs x 4 pad rows x 16
            const int d = t >> 6, rem = t & 63;
            const int row = 64 + (rem >> 4), c4 = rem & 15;
            ldsU[d * 1156 + row * 17 + c4] = (uint4){0u, 0u, 0u, 0u};
        }
    }
    __syncthreads();

    float m3[4], m4[4], m5[4];
    conv_g2<12,  0, 62>(lds, Bpack, b3, p, nth, l, m3);
    conv_g2<16, 12, 61>(lds, Bpack, b4, p, nth, l, m4);
    conv_g2<20, 28, 60>(lds, Bpack, b5, p, nth, l, m5);
    __syncthreads();                          // docs dead beyond this point

    float* feats = (float*)lds;               // [4][384] aliases doc buffer
    if ((l >> 4) == 0) {
        const int lm = l & 15;
        #pragma unroll
        for (int k = 0; k < 4; ++k) {
            const int c = nth * 64 + k * 16 + lm;
            feats[p * 384 +   0 + c] = m3[k];
            feats[p * 384 + 128 + c] = m4[k];
            feats[p * 384 + 256 + c] = m5[k];
        }
    }
    __syncthreads();

    if (t < 128) {
        const float4* wr4 = (const float4*)(fcw + (size_t)t * (3 * CC));
        float a0 = fcb[t], a1 = a0, a2 = a0, a3 = a0;
        for (int f4 = 0; f4 < 96; ++f4) {
            const float4 wv = wr4[f4];
            const float4 x0 = *(const float4*)&feats[0 * 384 + f4 * 4];
            const float4 x1 = *(const float4*)&feats[1 * 384 + f4 * 4];
            const float4 x2 = *(const float4*)&feats[2 * 384 + f4 * 4];
            const float4 x3 = *(const float4*)&feats[3 * 384 + f4 * 4];
            a0 += x0.x * wv.x + x0.y * wv.y + x0.z * wv.z + x0.w * wv.w;
            a1 += x1.x * wv.x + x1.y * wv.y + x1.z * wv.z + x1.w * wv.w;
            a2 += x2.x * wv.x + x2.y * wv.y + x2.z * wv.z + x2.w * wv.w;
            a3 += x3.x * wv.x + x3.y * wv.y + x3.z * wv.z + x3.w * wv.w;
        }
        out[(size_t)(n0 + 0) * EE + t] = a0;
        out[(size_t)(n0 + 1) * EE + t] = a1;
        out[(size_t)(n0 + 2) * EE + t] = a2;
        out[(size_t)(n0 + 3) * EE + t] = a3;
    }
}

// ---------------------------------------------------------------------------
extern "C" void kernel_launch(void* const* d_in, const int* in_sizes, int n_in,
                              void* d_out, int out_size, void* d_ws, size_t ws_size,
                              hipStream_t stream)
{
    const int*   word2news     = (const int*)d_in[0];
    const int*   word2news_len = (const int*)d_in[1];
    const int*   news_words    = (const int*)d_in[2];
    const float* table         = (const float*)d_in[3];
    const float* in_w          = (const float*)d_in[4];
    const float* in_b          = (const float*)d_in[5];
    const float* out_w         = (const float*)d_in[6];
    const float* out_b         = (const float*)d_in[7];
    const float* w3            = (const float*)d_in[8];
    const float* b3            = (const float*)d_in[9];
    const float* w4            = (const float*)d_in[10];
    const float* b4            = (const float*)d_in[11];
    const float* w5            = (const float*)d_in[12];
    const float* b5            = (const float*)d_in[13];
    const float* fcw           = (const float*)d_in[14];
    const float* fcb           = (const float*)d_in[15];

    float* out = (float*)d_out;
    u16* base  = (u16*)d_ws;
    u16* we16  = base;                                   // 2,560,000 u16 (5.12 MB)
    u16* Bpack = base + 2560000;                         //   196,608 u16
    u16* Kn16  = base + 2756608;                         // 1,048,576 u16
    u16* Wn16  = base + 3805184;                         // 1,048,576 u16 (Vn slot)
    u16* Qn16  = base + 4853760;                         // 1,048,576 u16 (11.80 MB)
    const size_t need_qn = (size_t)(4853760 + 1048576) * 2;

    pack_weights<<<48, 256, 0, stream>>>(w3, w4, w5, Bpack);

    if (ws_size >= need_qn) {
        kvqw_proj_kernel<<<NN / 8, 384, 0, stream>>>(table, in_w, in_b,
                                                     out_w, out_b,
                                                     Qn16, Kn16, Wn16);
        word_attn_wn<<<V_WORDS / WPB, 256, 0, stream>>>(
            word2news, word2news_len, Qn16, Kn16, Wn16, we16);
    } else {
        kv_proj_kernel<<<NN / 8, 256, 0, stream>>>(table, in_w, in_b, Kn16, Wn16);
        word_attn_kernel<<<V_WORDS / WPB, 256, 0, stream>>>(
            word2news, word2news_len, table, in_w, in_b, out_w, out_b,
            Kn16, Wn16, we16);
    }

    news_kernel<<<NN / 4, 512, 0, stream>>>(
        news_words, we16, Bpack, b3, b4, b5, fcw, fcb, out);
}